// Round 2
// baseline (1090.679 us; speedup 1.0000x reference)
//
#include <hip/hip_runtime.h>
#include <hip/hip_bf16.h>

// 3-layer Elman RNN, T=512, B=2048, H=32/64/64, OUT=26, fp32.
// One wave (64 lanes) owns 2 batch elements for all 512 timesteps.
// lane = hidden unit. Weights live in VGPRs/AGPRs in a DPP-permuted order;
// GEMV broadcast h[k]->all lanes uses v_fmac_f32_dpp row_ror:i (1 instr/MAC)
// plus ds_swizzle(xor16)/ds_bpermute(xor32) phase moves. A prep kernel derives
// the weight permutation by pushing laneid through the SAME permutation ops,
// so the main kernel is correct regardless of exact rotate direction.
// FC is half-packed (26<=32: lanes<32 = b0 rows, lanes>=32 = b1 rows) and
// software-pipelined one step late so its LDS chain overlaps L1/L2.

#define SEQ   512
#define BATCH 2048
#define OUTD  26
#define TBL_OFF (320*64)   // floats: weight slots (float4-packed), then table [27][32]

// ---------- cross-lane primitives ----------
#define SWZ_XOR16 0x401F   // BitMode: xor_mask=0x10, and_mask=0x1f -> lane^16 within 32-halves

__device__ __forceinline__ int swz16i(int v) {
  return __builtin_amdgcn_ds_swizzle(v, SWZ_XOR16);
}
__device__ __forceinline__ float swz16f(float v) {
  return __int_as_float(__builtin_amdgcn_ds_swizzle(__float_as_int(v), SWZ_XOR16));
}
__device__ __forceinline__ int xor32i(int addr, int v) {
  return __builtin_amdgcn_ds_bpermute(addr, v);
}
__device__ __forceinline__ float xor32f(int addr, float v) {
  return __int_as_float(__builtin_amdgcn_ds_bpermute(addr, __float_as_int(v)));
}
__device__ __forceinline__ float bpermf(int addr, float v) {
  return __int_as_float(__builtin_amdgcn_ds_bpermute(addr, __float_as_int(v)));
}

// DPP row_ror:I as a value permutation (prep only, derives weight order).
template<int I> __device__ __forceinline__ int rotI(int v) {
  if constexpr (I == 0) return v;
  else return __builtin_amdgcn_update_dpp(0, v, 0x120 + I, 0xF, 0xF, false);
}
__device__ int rot_sw(int v, int i) {
  switch (i & 15) {
    case 0:  return rotI<0>(v);   case 1:  return rotI<1>(v);
    case 2:  return rotI<2>(v);   case 3:  return rotI<3>(v);
    case 4:  return rotI<4>(v);   case 5:  return rotI<5>(v);
    case 6:  return rotI<6>(v);   case 7:  return rotI<7>(v);
    case 8:  return rotI<8>(v);   case 9:  return rotI<9>(v);
    case 10: return rotI<10>(v);  case 11: return rotI<11>(v);
    case 12: return rotI<12>(v);  case 13: return rotI<13>(v);
    case 14: return rotI<14>(v);  case 15: return rotI<15>(v);
  }
  return v;
}

// Fused FMA with DPP-rotated src0: acc += rot_i(h) * w. 1 instr/MAC.
template<int I> __device__ __forceinline__ void fma_rot(float& a, float h, float w) {
  if constexpr (I == 0) {
    a = __builtin_fmaf(h, w, a);
  } else {
    asm("v_fmac_f32_dpp %0, %1, %2 row_ror:%3 row_mask:0xf bank_mask:0xf"
        : "+v"(a) : "v"(h), "v"(w), "n"(I));
  }
}

#define ROW16(A, V, B)                       \
  fma_rot<0>(A, V, wreg[(B) + 0]);           \
  fma_rot<1>(A, V, wreg[(B) + 1]);           \
  fma_rot<2>(A, V, wreg[(B) + 2]);           \
  fma_rot<3>(A, V, wreg[(B) + 3]);           \
  fma_rot<4>(A, V, wreg[(B) + 4]);           \
  fma_rot<5>(A, V, wreg[(B) + 5]);           \
  fma_rot<6>(A, V, wreg[(B) + 6]);           \
  fma_rot<7>(A, V, wreg[(B) + 7]);           \
  fma_rot<8>(A, V, wreg[(B) + 8]);           \
  fma_rot<9>(A, V, wreg[(B) + 9]);           \
  fma_rot<10>(A, V, wreg[(B) + 10]);         \
  fma_rot<11>(A, V, wreg[(B) + 11]);         \
  fma_rot<12>(A, V, wreg[(B) + 12]);         \
  fma_rot<13>(A, V, wreg[(B) + 13]);         \
  fma_rot<14>(A, V, wreg[(B) + 14]);         \
  fma_rot<15>(A, V, wreg[(B) + 15]);

// Full 64-col GEMV with precomputed phase values {V, xor16, xor32, xor16*xor32}.
#define GEMV64P(A, A2, V, V16, V32, V48, B) do { \
    ROW16(A,  V,   (B));        \
    ROW16(A2, V16, (B)+16);     \
    ROW16(A,  V32, (B)+32);     \
    ROW16(A2, V48, (B)+48);     \
  } while (0)

// ---------- guarded producers (DPP read-after-VALU-write hazard: 2 wait states) ----------
__device__ __forceinline__ float mul_guard(float a, float b) {
  float r;
  asm("v_mul_f32 %0, %1, %2\n\ts_nop 1" : "=v"(r) : "v"(a), "v"(b));
  return r;
}
__device__ __forceinline__ float guard_val(float x) {
  float r;
  asm("v_mov_b32 %0, %1\n\ts_nop 1" : "=v"(r) : "v"(x));
  return r;
}

__device__ __forceinline__ float tanh_u(float x) {  // ~1ulp: exp + NR-refined rcp
  x = fminf(10.f, fmaxf(-10.f, x));
  float e = __expf(-2.f * x);
  float d = 1.f + e;
  float r = __builtin_amdgcn_rcpf(d);
  r = r * (2.f - d * r);
  return (1.f - e) * r;
}
__device__ __forceinline__ float tanh_g(float x) {  // guarded final mul (feeds DPP soon)
  x = fminf(10.f, fmaxf(-10.f, x));
  float e = __expf(-2.f * x);
  float d = 1.f + e;
  float r = __builtin_amdgcn_rcpf(d);
  r = r * (2.f - d * r);
  return mul_guard(1.f - e, r);
}

// ---------- prep kernel: weight permutation + vocab table ----------
// Slot regions: [0,32) L1 Whh1 | [32,64) L2A Wih2 | [64,128) L2B Whh2
//   [128,192) L3A Wih3 | [192,256) L3B Whh3 | [256,320) FC Wfc (half-packed)
// Slot s stored float4-packed: ws[(s>>2)*256 + lane*4 + (s&3)].
__global__ __launch_bounds__(64) void prep_kernel(
    const float* __restrict__ emb,
    const float* __restrict__ Wih1, const float* __restrict__ Whh1,
    const float* __restrict__ bih1, const float* __restrict__ bhh1,
    const float* __restrict__ Wih2, const float* __restrict__ Whh2,
    const float* __restrict__ Wih3, const float* __restrict__ Whh3,
    const float* __restrict__ Wfc,  float* __restrict__ ws) {
  const int lane  = threadIdx.x;
  const int xaddr = ((lane ^ 32) << 2);
  const int s     = blockIdx.x;

  if (s < 320) {
    const float* Wp; int ncol, row, v, p, local, colbase = 0;
    if (s < 32)       { local = s;       v = lane;      Wp = Whh1; ncol = 32; row = lane & 31; p = local >> 4; }
    else if (s < 64)  { local = s - 32;  v = lane & 31; Wp = Wih2; ncol = 32; row = lane;      p = local >> 4; }
    else if (s < 128) { local = s - 64;  v = lane;      Wp = Whh2; ncol = 64; row = lane;      p = local >> 4; }
    else if (s < 192) { local = s - 128; v = lane;      Wp = Wih3; ncol = 64; row = lane;      p = local >> 4; }
    else if (s < 256) { local = s - 192; v = lane;      Wp = Whh3; ncol = 64; row = lane;      p = local >> 4; }
    else              { local = s - 256; v = lane;      Wp = Wfc;  ncol = 64; row = lane & 31;
                        p = (local >> 4) & 1; colbase = (local >> 5) * 32; }
    int i = local & 15;

    int pv;
    switch (p) {
      case 0: pv = v; break;
      case 1: pv = swz16i(v); break;
      case 2: pv = xor32i(xaddr, v); break;
      default: pv = swz16i(xor32i(xaddr, v)); break;
    }
    int pi = rot_sw(pv, i);

    float w;
    if (s >= 256) {
      int col = (pi & 31) + colbase;
      w = (row < OUTD) ? Wp[row * 64 + col] : 0.f;   // zero-pad rows 26..31
    } else {
      int col = pi & (ncol - 1);
      w = Wp[row * ncol + col];
    }
    ws[(s >> 2) * 256 + lane * 4 + (s & 3)] = w;
  } else {
    // vocab table: tbl[v][j] = emb[v]·W_ih1[j] + b_ih1[j] + b_hh1[j]
    int idx = (s - 320) * 64 + lane;
    if (idx < 27 * 32) {
      int vv = idx >> 5, j = idx & 31;
      float acc = bih1[j] + bhh1[j];
      for (int e = 0; e < 20; ++e) acc += emb[vv * 20 + e] * Wih1[j * 20 + e];
      ws[TBL_OFF + idx] = acc;
    }
  }
}

// ---------- main fused RNN kernel: 1 wave per 2 batch elements ----------
__global__ __launch_bounds__(64, 1) void rnn_main(
    const int*   __restrict__ x,
    const float* __restrict__ bih2, const float* __restrict__ bhh2,
    const float* __restrict__ bih3, const float* __restrict__ bhh3,
    const float* __restrict__ bfc,
    const float* __restrict__ ws,   float* __restrict__ out) {
  __shared__ float tbl[27 * 32];
  const int lane  = threadIdx.x;
  const int xaddr = ((lane ^ 32) << 2);     // bpermute addr: lane^32
  const int alo   = (lane & 31) << 2;       // bpermute addr: lane&31  (b0 replicate)
  const int ahi   = alo + 128;              // bpermute addr: (lane&31)|32 (b1 replicate)

  for (int idx = lane; idx < 27 * 32; idx += 64) tbl[idx] = ws[TBL_OFF + idx];
  __syncthreads();

  // 320 weight slots -> registers (all constant-indexed; ~110 land in AGPRs)
  float wreg[320];
  const float4* wsv = (const float4*)ws;
#pragma unroll
  for (int g = 0; g < 80; ++g) {
    float4 q = wsv[g * 64 + lane];
    wreg[4*g+0] = q.x; wreg[4*g+1] = q.y; wreg[4*g+2] = q.z; wreg[4*g+3] = q.w;
  }

  const int b0   = blockIdx.x * 2;
  const int bsel = b0 + (lane >> 5);        // lanes 0-31 -> b0, 32-63 -> b1
  const int jlow = lane & 31;

  const float beta2  = bih2[lane] + bhh2[lane];
  const float beta3  = bih3[lane] + bhh3[lane];
  const float betafc = (jlow < OUTD) ? bfc[jlow] : 0.f;

  // loop-carried state: value + its 3 phase-permuted companions
  float vh1 = 0.f, v1s = 0.f;
  float h20 = 0.f, h20a = 0.f, h20b = 0.f, h20c = 0.f;
  float h21 = 0.f, h21a = 0.f, h21b = 0.f, h21c = 0.f;
  float h30 = 0.f, h30a = 0.f, h30b = 0.f, h30c = 0.f;
  float h31 = 0.f, h31a = 0.f, h31b = 0.f, h31c = 0.f;

  int   xv_nxt;
  float tblv_cur;
  {
    int xv0  = x[bsel];
    tblv_cur = tbl[xv0 * 32 + jlow];
    xv_nxt   = x[BATCH + bsel];
  }
  float* outbase = out + (size_t)bsel * OUTD + jlow;

#pragma unroll 1
  for (int t = 0; t < SEQ; ++t) {
    int tpre   = (t + 2 < SEQ) ? (t + 2) : (SEQ - 1);
    int xv_pre = x[(size_t)tpre * BATCH + bsel];

    // ===== FC for step t-1 (pipelined; t=0 writes junk to row 0, overwritten at t=1) =====
    {
      float vm0  = guard_val((lane < 32) ? h30  : h31b);  // [h3_b0[0..31] | h3_b1[0..31]]
      float vm1  = guard_val((lane < 32) ? h30b : h31 );  // [h3_b0[32..63]| h3_b1[32..63]]
      float vm0s = swz16f(vm0);
      float vm1s = swz16f(vm1);
      float af = betafc, afb = 0.f;
      ROW16(af,  vm0,  256);  ROW16(afb, vm0s, 272);
      ROW16(af,  vm1,  288);  ROW16(afb, vm1s, 304);
      float ov  = af + afb;                // lanes<32: b0 rows; lanes>=32: b1 rows
      int tout  = (t == 0) ? 0 : t - 1;
      if (jlow < OUTD) outbase[(size_t)tout * (BATCH * OUTD)] = ov;
    }

    // ===== layer 1 (packed halves; K=32) =====
    float a1a = tblv_cur, a1b = 0.f;
    ROW16(a1a, vh1, 0);
    ROW16(a1b, v1s, 16);
    float h1n = tanh_u(a1a + a1b);

    float tblv_n = tbl[xv_nxt * 32 + jlow];
    float hb0  = bpermf(alo, h1n);        // h1_b0[lane&31] on all lanes
    float hb1  = bpermf(ahi, h1n);        // h1_b1[lane&31] on all lanes
    float v1s_n = swz16f(h1n);
    float hb0s = swz16f(hb0);
    float hb1s = swz16f(hb1);

    // ===== layer 2 (K = 32 [h1] + 64 [h2 old]) =====
    float a20 = beta2, a20b = 0.f, a21 = beta2, a21b = 0.f;
    ROW16(a20, hb0, 32);  ROW16(a20b, hb0s, 48);
    ROW16(a21, hb1, 32);  ROW16(a21b, hb1s, 48);
    GEMV64P(a20, a20b, h20, h20a, h20b, h20c, 64);
    GEMV64P(a21, a21b, h21, h21a, h21b, h21c, 64);
    float h2n0 = tanh_g(a20 + a20b);
    float h2n1 = tanh_g(a21 + a21b);
    float h2n0b = xor32f(xaddr, h2n0);
    float h2n0a = swz16f(h2n0);
    float h2n0c = swz16f(h2n0b);
    float h2n1b = xor32f(xaddr, h2n1);
    float h2n1a = swz16f(h2n1);
    float h2n1c = swz16f(h2n1b);

    // ===== layer 3 (K = 64 [h2 new] + 64 [h3 old]) =====
    float a30 = beta3, a30b = 0.f, a31 = beta3, a31b = 0.f;
    GEMV64P(a30, a30b, h2n0, h2n0a, h2n0b, h2n0c, 128);
    GEMV64P(a31, a31b, h2n1, h2n1a, h2n1b, h2n1c, 128);
    GEMV64P(a30, a30b, h30, h30a, h30b, h30c, 192);
    GEMV64P(a31, a31b, h31, h31a, h31b, h31c, 192);
    float h3n0 = tanh_u(a30 + a30b);
    float h3n1 = tanh_u(a31 + a31b);
    float h3n0b = xor32f(xaddr, h3n0);
    float h3n0a = swz16f(h3n0);
    float h3n0c = swz16f(h3n0b);
    float h3n1b = xor32f(xaddr, h3n1);
    float h3n1a = swz16f(h3n1);
    float h3n1c = swz16f(h3n1b);

    // commit
    vh1 = h1n;  v1s = v1s_n;
    h20 = h2n0; h20a = h2n0a; h20b = h2n0b; h20c = h2n0c;
    h21 = h2n1; h21a = h2n1a; h21b = h2n1b; h21c = h2n1c;
    h30 = h3n0; h30a = h3n0a; h30b = h3n0b; h30c = h3n0c;
    h31 = h3n1; h31a = h3n1a; h31b = h3n1b; h31c = h3n1c;
    xv_nxt = xv_pre; tblv_cur = tblv_n;
  }

  // ===== epilogue FC for t = 511 =====
  {
    float vm0  = guard_val((lane < 32) ? h30  : h31b);
    float vm1  = guard_val((lane < 32) ? h30b : h31 );
    float vm0s = swz16f(vm0);
    float vm1s = swz16f(vm1);
    float af = betafc, afb = 0.f;
    ROW16(af,  vm0,  256);  ROW16(afb, vm0s, 272);
    ROW16(af,  vm1,  288);  ROW16(afb, vm1s, 304);
    if (jlow < OUTD) outbase[(size_t)(SEQ - 1) * (BATCH * OUTD)] = af + afb;
  }
}

extern "C" void kernel_launch(void* const* d_in, const int* in_sizes, int n_in,
                              void* d_out, int out_size, void* d_ws, size_t ws_size,
                              hipStream_t stream) {
  const int*   x    = (const int*)  d_in[0];
  const float* emb  = (const float*)d_in[1];
  const float* Wih1 = (const float*)d_in[2];
  const float* Whh1 = (const float*)d_in[3];
  const float* bih1 = (const float*)d_in[4];
  const float* bhh1 = (const float*)d_in[5];
  const float* Wih2 = (const float*)d_in[6];
  const float* Whh2 = (const float*)d_in[7];
  const float* bih2 = (const float*)d_in[8];
  const float* bhh2 = (const float*)d_in[9];
  const float* Wih3 = (const float*)d_in[10];
  const float* Whh3 = (const float*)d_in[11];
  const float* bih3 = (const float*)d_in[12];
  const float* bhh3 = (const float*)d_in[13];
  const float* Wfc  = (const float*)d_in[14];
  const float* bfc  = (const float*)d_in[15];
  float* ws  = (float*)d_ws;
  float* out = (float*)d_out;

  prep_kernel<<<334, 64, 0, stream>>>(emb, Wih1, Whh1, bih1, bhh1,
                                      Wih2, Whh2, Wih3, Whh3, Wfc, ws);
  rnn_main<<<BATCH / 2, 64, 0, stream>>>(x, bih2, bhh2, bih3, bhh3, bfc, ws, out);
}

// Round 4
// 856.805 us; speedup vs baseline: 1.2730x; 1.2730x over previous
//
#include <hip/hip_runtime.h>
#include <hip/hip_bf16.h>

// 3-layer Elman RNN, T=512, B=2048, H=32/64/64, OUT=26, fp32.
// Wave-specialized 2-wave pipeline: each 128-thread workgroup owns 2 batch
// elements. Wave A computes L1+L2 (+batch0's L3 input-proj); wave B computes
// L3 recurrence (+batch1's L3 input-proj) + FC, one step behind, fed via a
// double-buffered LDS slot (3 floats/lane/step) + one __syncthreads per step.
// Each wave holds 192 weight slots -> fully VGPR-resident (no AGPR copies,
// which doubled VALU issue in the 1-wave/320-slot version: 180 VGPR + ~1550
// VALU instr/step measured vs ~650 static).
// GEMV broadcast uses v_fmac_f32_dpp row_ror:i (1 instr/MAC) + ds_swizzle
// (xor16) / ds_bpermute (xor32) phase moves. Prep kernel derives the weight
// permutation by pushing laneid through the SAME permutation ops.

#define SEQ   512
#define BATCH 2048
#define OUTD  26
#define NSLOT 384                 // 192 per wave
#define TBL_OFF (NSLOT*64)        // floats: slots (float4-packed), then table [27][32]

// ---------- cross-lane primitives ----------
#define SWZ_XOR16 0x401F   // BitMode: xor_mask=0x10, and_mask=0x1f -> lane^16 within 32-halves

__device__ __forceinline__ int swz16i(int v) {
  return __builtin_amdgcn_ds_swizzle(v, SWZ_XOR16);
}
__device__ __forceinline__ float swz16f(float v) {
  return __int_as_float(__builtin_amdgcn_ds_swizzle(__float_as_int(v), SWZ_XOR16));
}
__device__ __forceinline__ int xor32i(int addr, int v) {
  return __builtin_amdgcn_ds_bpermute(addr, v);
}
__device__ __forceinline__ float xor32f(int addr, float v) {
  return __int_as_float(__builtin_amdgcn_ds_bpermute(addr, __float_as_int(v)));
}
__device__ __forceinline__ float bpermf(int addr, float v) {
  return __int_as_float(__builtin_amdgcn_ds_bpermute(addr, __float_as_int(v)));
}

// DPP row_ror:I as a value permutation (prep only; derives weight order).
template<int I> __device__ __forceinline__ int rotI(int v) {
  if constexpr (I == 0) return v;
  else return __builtin_amdgcn_update_dpp(0, v, 0x120 + I, 0xF, 0xF, false);
}
__device__ int rot_sw(int v, int i) {
  switch (i & 15) {
    case 0:  return rotI<0>(v);   case 1:  return rotI<1>(v);
    case 2:  return rotI<2>(v);   case 3:  return rotI<3>(v);
    case 4:  return rotI<4>(v);   case 5:  return rotI<5>(v);
    case 6:  return rotI<6>(v);   case 7:  return rotI<7>(v);
    case 8:  return rotI<8>(v);   case 9:  return rotI<9>(v);
    case 10: return rotI<10>(v);  case 11: return rotI<11>(v);
    case 12: return rotI<12>(v);  case 13: return rotI<13>(v);
    case 14: return rotI<14>(v);  case 15: return rotI<15>(v);
  }
  return v;
}

// Fused FMA with DPP-rotated src0: acc += rot_i(h) * w. 1 instr/MAC.
template<int I> __device__ __forceinline__ void fma_rot(float& a, float h, float w) {
  if constexpr (I == 0) {
    a = __builtin_fmaf(h, w, a);
  } else {
    asm("v_fmac_f32_dpp %0, %1, %2 row_ror:%3 row_mask:0xf bank_mask:0xf"
        : "+v"(a) : "v"(h), "v"(w), "n"(I));
  }
}

#define ROW16(A, V, B)                       \
  fma_rot<0>(A, V, wreg[(B) + 0]);           \
  fma_rot<1>(A, V, wreg[(B) + 1]);           \
  fma_rot<2>(A, V, wreg[(B) + 2]);           \
  fma_rot<3>(A, V, wreg[(B) + 3]);           \
  fma_rot<4>(A, V, wreg[(B) + 4]);           \
  fma_rot<5>(A, V, wreg[(B) + 5]);           \
  fma_rot<6>(A, V, wreg[(B) + 6]);           \
  fma_rot<7>(A, V, wreg[(B) + 7]);           \
  fma_rot<8>(A, V, wreg[(B) + 8]);           \
  fma_rot<9>(A, V, wreg[(B) + 9]);           \
  fma_rot<10>(A, V, wreg[(B) + 10]);         \
  fma_rot<11>(A, V, wreg[(B) + 11]);         \
  fma_rot<12>(A, V, wreg[(B) + 12]);         \
  fma_rot<13>(A, V, wreg[(B) + 13]);         \
  fma_rot<14>(A, V, wreg[(B) + 14]);         \
  fma_rot<15>(A, V, wreg[(B) + 15]);

// Full 64-col GEMV with precomputed phase values {V, xor16, xor32, xor16*xor32}.
#define GEMV64P(A, A2, V, V16, V32, V48, B) do { \
    ROW16(A,  V,   (B));        \
    ROW16(A2, V16, (B)+16);     \
    ROW16(A,  V32, (B)+32);     \
    ROW16(A2, V48, (B)+48);     \
  } while (0)

// ---------- guarded producers (VALU-write -> DPP-read needs 2 wait states) ----------
__device__ __forceinline__ float mul_guard(float a, float b) {
  float r;
  asm("v_mul_f32 %0, %1, %2\n\ts_nop 1" : "=v"(r) : "v"(a), "v"(b));
  return r;
}
__device__ __forceinline__ float guard_val(float x) {
  float r;
  asm("v_mov_b32 %0, %1\n\ts_nop 1" : "=v"(r) : "v"(x));
  return r;
}

__device__ __forceinline__ float tanh_u(float x) {  // exp + NR-refined rcp
  x = fminf(10.f, fmaxf(-10.f, x));
  float e = __expf(-2.f * x);
  float d = 1.f + e;
  float r = __builtin_amdgcn_rcpf(d);
  r = r * (2.f - d * r);
  return (1.f - e) * r;
}
__device__ __forceinline__ float tanh_g(float x) {  // guarded final mul (feeds DPP soon)
  x = fminf(10.f, fmaxf(-10.f, x));
  float e = __expf(-2.f * x);
  float d = 1.f + e;
  float r = __builtin_amdgcn_rcpf(d);
  r = r * (2.f - d * r);
  return mul_guard(1.f - e, r);
}

// ---------- prep kernel: weight permutation + vocab table ----------
// Global slot regions (A = [0,192), B = [192,384)):
//  [0,32)    Whh1 (2-phase, packed halves)     A
//  [32,64)   Wih2 (2-phase, v=lane&31)         A
//  [64,128)  Whh2 (4-phase)                    A
//  [128,192) Wih3 (4-phase)                    A
//  [192,256) Whh3 (4-phase)                    B
//  [256,320) Wih3 copy (4-phase)               B
//  [320,384) Wfc  (half-packed, 2-phase x2)    B
// Slot s stored float4-packed: ws[(s>>2)*256 + lane*4 + (s&3)].
__global__ __launch_bounds__(64) void prep_kernel(
    const float* __restrict__ emb,
    const float* __restrict__ Wih1, const float* __restrict__ Whh1,
    const float* __restrict__ bih1, const float* __restrict__ bhh1,
    const float* __restrict__ Wih2, const float* __restrict__ Whh2,
    const float* __restrict__ Wih3, const float* __restrict__ Whh3,
    const float* __restrict__ Wfc,  float* __restrict__ ws) {
  const int lane  = threadIdx.x;
  const int xaddr = ((lane ^ 32) << 2);
  const int s     = blockIdx.x;

  if (s < NSLOT) {
    const float* Wp; int ncol, row, v, p, local, colbase = 0;
    if (s < 32)       { local = s;       v = lane;      Wp = Whh1; ncol = 32; row = lane & 31; p = local >> 4; }
    else if (s < 64)  { local = s - 32;  v = lane & 31; Wp = Wih2; ncol = 32; row = lane;      p = local >> 4; }
    else if (s < 128) { local = s - 64;  v = lane;      Wp = Whh2; ncol = 64; row = lane;      p = local >> 4; }
    else if (s < 192) { local = s - 128; v = lane;      Wp = Wih3; ncol = 64; row = lane;      p = local >> 4; }
    else if (s < 256) { local = s - 192; v = lane;      Wp = Whh3; ncol = 64; row = lane;      p = local >> 4; }
    else if (s < 320) { local = s - 256; v = lane;      Wp = Wih3; ncol = 64; row = lane;      p = local >> 4; }
    else              { local = s - 320; v = lane;      Wp = Wfc;  ncol = 64; row = lane & 31;
                        p = (local >> 4) & 1; colbase = (local >> 5) * 32; }
    int i = local & 15;

    int pv;
    switch (p) {
      case 0: pv = v; break;
      case 1: pv = swz16i(v); break;
      case 2: pv = xor32i(xaddr, v); break;
      default: pv = swz16i(xor32i(xaddr, v)); break;
    }
    int pi = rot_sw(pv, i);

    float w;
    if (s >= 320) {
      int col = (pi & 31) + colbase;
      w = (row < OUTD) ? Wp[row * 64 + col] : 0.f;   // zero-pad rows 26..31
    } else {
      int col = pi & (ncol - 1);
      w = Wp[row * ncol + col];
    }
    ws[(s >> 2) * 256 + lane * 4 + (s & 3)] = w;
  } else {
    // vocab table: tbl[v][j] = emb[v]*W_ih1[j] + b_ih1[j] + b_hh1[j]
    int idx = (s - NSLOT) * 64 + lane;
    if (idx < 27 * 32) {
      int vv = idx >> 5, j = idx & 31;
      float acc = bih1[j] + bhh1[j];
      for (int e = 0; e < 20; ++e) acc += emb[vv * 20 + e] * Wih1[j * 20 + e];
      ws[TBL_OFF + idx] = acc;
    }
  }
}

// ---------- main fused RNN kernel: 2 waves (A,B) per 2 batch elements ----------
__global__ __launch_bounds__(128, 2) void rnn_main(
    const int*   __restrict__ x,
    const float* __restrict__ bih2, const float* __restrict__ bhh2,
    const float* __restrict__ bih3, const float* __restrict__ bhh3,
    const float* __restrict__ bfc,
    const float* __restrict__ ws,   float* __restrict__ out) {
  __shared__ float tbl[27 * 32];
  __shared__ float cbuf[2][3][64];   // double-buffered A->B: {h2_b1, p0, p0b}

  const int tid   = threadIdx.x;
  const int lane  = tid & 63;
  const bool wA   = (tid < 64);
  const int xaddr = ((lane ^ 32) << 2);
  const int alo   = (lane & 31) << 2;
  const int ahi   = alo + 128;
  const int jlow  = lane & 31;

  for (int idx = tid; idx < 27 * 32; idx += 128) tbl[idx] = ws[TBL_OFF + idx];

  // 192 weight slots per wave -> VGPR-resident (constant-indexed only)
  float wreg[192];
  {
    const float4* wsv = (const float4*)ws;
    const int gbase = wA ? 0 : 48;
#pragma unroll
    for (int g = 0; g < 48; ++g) {
      float4 q = wsv[(gbase + g) * 64 + lane];
      wreg[4*g+0] = q.x; wreg[4*g+1] = q.y; wreg[4*g+2] = q.z; wreg[4*g+3] = q.w;
    }
  }
  __syncthreads();

  const int b0   = blockIdx.x * 2;
  const int bsel = b0 + (lane >> 5);        // lanes 0-31 -> b0, 32-63 -> b1

  const float beta2  = bih2[lane] + bhh2[lane];
  const float beta3  = bih3[lane] + bhh3[lane];
  const float betafc = (jlow < OUTD) ? bfc[jlow] : 0.f;

  // Wave-A state
  float vh1 = 0.f, v1s = 0.f;
  float h20 = 0.f, h20a = 0.f, h20b = 0.f, h20c = 0.f;
  float h21 = 0.f, h21a = 0.f, h21b = 0.f, h21c = 0.f;
  // Wave-B state
  float h30 = 0.f, h30a = 0.f, h30b = 0.f, h30c = 0.f;
  float h31 = 0.f, h31a = 0.f, h31b = 0.f, h31c = 0.f;

  int   xv_nxt = 0;
  float tblv_cur = 0.f;
  if (wA) {
    int xv0  = x[bsel];
    tblv_cur = tbl[xv0 * 32 + jlow];
    xv_nxt   = x[BATCH + bsel];
  }
  float* outbase = out + (size_t)bsel * OUTD + jlow;

#pragma unroll 1
  for (int i = 0; i <= SEQ; ++i) {
    __syncthreads();
    if (wA) {
      if (i < SEQ) {
        int tpre   = (i + 2 < SEQ) ? (i + 2) : (SEQ - 1);
        int xv_pre = x[(size_t)tpre * BATCH + bsel];

        // ===== layer 1 (packed halves; K=32) =====
        float a1a = tblv_cur, a1b = 0.f;
        ROW16(a1a, vh1, 0);
        ROW16(a1b, v1s, 16);
        float h1n = tanh_u(a1a + a1b);

        float tblv_n = tbl[xv_nxt * 32 + jlow];
        float hb0  = bpermf(alo, h1n);        // h1_b0[lane&31] on all lanes
        float hb1  = bpermf(ahi, h1n);        // h1_b1[lane&31] on all lanes
        float v1s_n = swz16f(h1n);
        float hb0s = swz16f(hb0);
        float hb1s = swz16f(hb1);

        // ===== layer 2 (K = 32 [h1] + 64 [h2 old]) =====
        float a20 = beta2, a20b = 0.f, a21 = beta2, a21b = 0.f;
        ROW16(a20, hb0, 32);  ROW16(a20b, hb0s, 48);
        ROW16(a21, hb1, 32);  ROW16(a21b, hb1s, 48);
        GEMV64P(a20, a20b, h20, h20a, h20b, h20c, 64);
        GEMV64P(a21, a21b, h21, h21a, h21b, h21c, 64);
        float h2n0 = tanh_g(a20 + a20b);      // feeds DPP below -> guarded
        float h2n1 = tanh_u(a21 + a21b);

        float h2n0b = xor32f(xaddr, h2n0);
        float h2n0a = swz16f(h2n0);
        float h2n0c = swz16f(h2n0b);
        float h2n1b = xor32f(xaddr, h2n1);
        float h2n1a = swz16f(h2n1);
        float h2n1c = swz16f(h2n1b);

        // ===== L3 input-projection for batch0 (partial for wave B) =====
        float p0 = beta3, p0b = 0.f;
        GEMV64P(p0, p0b, h2n0, h2n0a, h2n0b, h2n0c, 128);

        cbuf[i & 1][0][lane] = h2n1;
        cbuf[i & 1][1][lane] = p0;
        cbuf[i & 1][2][lane] = p0b;

        // commit
        vh1 = h1n;  v1s = v1s_n;
        h20 = h2n0; h20a = h2n0a; h20b = h2n0b; h20c = h2n0c;
        h21 = h2n1; h21a = h2n1a; h21b = h2n1b; h21c = h2n1c;
        xv_nxt = xv_pre; tblv_cur = tblv_n;
      }
    } else {
      if (i > 0) {
        const int rb = (i - 1) & 1;
        float h2n1 = cbuf[rb][0][lane];
        float p0   = cbuf[rb][1][lane];
        float p0b  = cbuf[rb][2][lane];

        // ===== L3 recurrence (independent of LDS reads -> hides latency) =====
        float a30 = 0.f, a30b = 0.f, a31 = beta3, a31b = 0.f;
        GEMV64P(a30, a30b, h30, h30a, h30b, h30c, 0);
        GEMV64P(a31, a31b, h31, h31a, h31b, h31c, 0);

        // ===== L3 input-projection for batch1 =====
        float h2n1b = xor32f(xaddr, h2n1);
        float h2n1a = swz16f(h2n1);
        float h2n1c = swz16f(h2n1b);
        GEMV64P(a31, a31b, h2n1, h2n1a, h2n1b, h2n1c, 64);

        float h3n0 = tanh_u((p0 + p0b) + (a30 + a30b));
        float h3n1 = tanh_u(a31 + a31b);

        float h3n0b = xor32f(xaddr, h3n0);
        float h3n0a = swz16f(h3n0);
        float h3n0c = swz16f(h3n0b);
        float h3n1b = xor32f(xaddr, h3n1);
        float h3n1a = swz16f(h3n1);
        float h3n1c = swz16f(h3n1b);

        // ===== FC (half-packed: lanes<32 = b0 rows, lanes>=32 = b1 rows) =====
        float vm0  = guard_val((lane < 32) ? h3n0  : h3n1b);  // cols 0..31
        float vm1  = guard_val((lane < 32) ? h3n0b : h3n1 );  // cols 32..63
        float vm0s = swz16f(vm0);
        float vm1s = swz16f(vm1);
        float af = betafc, afb = 0.f;
        ROW16(af,  vm0,  128);  ROW16(afb, vm0s, 144);
        ROW16(af,  vm1,  160);  ROW16(afb, vm1s, 176);
        if (jlow < OUTD) outbase[(size_t)(i - 1) * (BATCH * OUTD)] = af + afb;

        h30 = h3n0; h30a = h3n0a; h30b = h3n0b; h30c = h3n0c;
        h31 = h3n1; h31a = h3n1a; h31b = h3n1b; h31c = h3n1c;
      }
    }
  }
}

extern "C" void kernel_launch(void* const* d_in, const int* in_sizes, int n_in,
                              void* d_out, int out_size, void* d_ws, size_t ws_size,
                              hipStream_t stream) {
  const int*   x    = (const int*)  d_in[0];
  const float* emb  = (const float*)d_in[1];
  const float* Wih1 = (const float*)d_in[2];
  const float* Whh1 = (const float*)d_in[3];
  const float* bih1 = (const float*)d_in[4];
  const float* bhh1 = (const float*)d_in[5];
  const float* Wih2 = (const float*)d_in[6];
  const float* Whh2 = (const float*)d_in[7];
  const float* bih2 = (const float*)d_in[8];
  const float* bhh2 = (const float*)d_in[9];
  const float* Wih3 = (const float*)d_in[10];
  const float* Whh3 = (const float*)d_in[11];
  const float* bih3 = (const float*)d_in[12];
  const float* bhh3 = (const float*)d_in[13];
  const float* Wfc  = (const float*)d_in[14];
  const float* bfc  = (const float*)d_in[15];
  float* ws  = (float*)d_ws;
  float* out = (float*)d_out;

  prep_kernel<<<NSLOT + 14, 64, 0, stream>>>(emb, Wih1, Whh1, bih1, bhh1,
                                             Wih2, Whh2, Wih3, Whh3, Wfc, ws);
  rnn_main<<<BATCH / 2, 128, 0, stream>>>(x, bih2, bhh2, bih3, bhh3, bfc, ws, out);
}

// Round 5
// 846.990 us; speedup vs baseline: 1.2877x; 1.0116x over previous
//
#include <hip/hip_runtime.h>
#include <hip/hip_bf16.h>

// 3-layer Elman RNN, T=512, B=2048, H=32/64/64, OUT=26, fp32.
// Wave-specialized 2-wave pipeline (wave A: L1+L2+L3-proj(b0); wave B: L3
// recurrence + L3-proj(b1) + FC, one step behind; double-buffered LDS float2
// handoff, one __syncthreads per step). 192 weight slots per wave in VGPRs.
// THIS ROUND: break FMA dependency chains -- every 16-rotation GEMV block is
// emitted round-robin across 4 independent accumulators (dep distance 4 instr
// = 8 cyc > 4 cyc FMA latency), and every cross-lane companion is a SINGLE
// ds_bpermute hop (lane^16 / lane^32 / lane^48) issued right after its
// producer and consumed >=128 independent fmacs later.
// GEMV broadcast uses v_fmac_f32_dpp row_ror:i (1 instr/MAC). Prep kernel
// derives the weight permutation by pushing laneid through the SAME
// permutation ops, so exact DPP rotate direction is irrelevant.

#define SEQ   512
#define BATCH 2048
#define OUTD  26
#define NSLOT 384                 // 192 per wave
#define TBL_OFF (NSLOT*64)        // floats: slots (float4-packed), then table [27][32]

// ---------- cross-lane primitives ----------
#define SWZ_XOR16 0x401F   // BitMode: xor_mask=0x10, and_mask=0x1f

__device__ __forceinline__ int swz16i(int v) {
  return __builtin_amdgcn_ds_swizzle(v, SWZ_XOR16);
}
__device__ __forceinline__ int xor32i(int addr, int v) {
  return __builtin_amdgcn_ds_bpermute(addr, v);
}
__device__ __forceinline__ float bpermf(int addr, float v) {
  return __int_as_float(__builtin_amdgcn_ds_bpermute(addr, __float_as_int(v)));
}

// DPP row_ror:I as a value permutation (prep only; derives weight order).
template<int I> __device__ __forceinline__ int rotI(int v) {
  if constexpr (I == 0) return v;
  else return __builtin_amdgcn_update_dpp(0, v, 0x120 + I, 0xF, 0xF, false);
}
__device__ int rot_sw(int v, int i) {
  switch (i & 15) {
    case 0:  return rotI<0>(v);   case 1:  return rotI<1>(v);
    case 2:  return rotI<2>(v);   case 3:  return rotI<3>(v);
    case 4:  return rotI<4>(v);   case 5:  return rotI<5>(v);
    case 6:  return rotI<6>(v);   case 7:  return rotI<7>(v);
    case 8:  return rotI<8>(v);   case 9:  return rotI<9>(v);
    case 10: return rotI<10>(v);  case 11: return rotI<11>(v);
    case 12: return rotI<12>(v);  case 13: return rotI<13>(v);
    case 14: return rotI<14>(v);  case 15: return rotI<15>(v);
  }
  return v;
}

// Fused FMA with DPP-rotated src0: acc += rot_i(h) * w. 1 instr/MAC.
template<int I> __device__ __forceinline__ void fma_rot(float& a, float h, float w) {
  if constexpr (I == 0) {
    a = __builtin_fmaf(h, w, a);
  } else {
    asm("v_fmac_f32_dpp %0, %1, %2 row_ror:%3 row_mask:0xf bank_mask:0xf"
        : "+v"(a) : "v"(h), "v"(w), "n"(I));
  }
}

// ---- 4-chain interleaved emission: dep distance 4 instructions ----
#define I4(i, A0,V0,B0, A1,V1,B1, A2,V2,B2, A3,V3,B3) \
  fma_rot<(i)>(A0, V0, wreg[(B0)+(i)]); \
  fma_rot<(i)>(A1, V1, wreg[(B1)+(i)]); \
  fma_rot<(i)>(A2, V2, wreg[(B2)+(i)]); \
  fma_rot<(i)>(A3, V3, wreg[(B3)+(i)]);

#define R16_I4(A0,V0,B0, A1,V1,B1, A2,V2,B2, A3,V3,B3) \
  I4(0, A0,V0,B0, A1,V1,B1, A2,V2,B2, A3,V3,B3) \
  I4(1, A0,V0,B0, A1,V1,B1, A2,V2,B2, A3,V3,B3) \
  I4(2, A0,V0,B0, A1,V1,B1, A2,V2,B2, A3,V3,B3) \
  I4(3, A0,V0,B0, A1,V1,B1, A2,V2,B2, A3,V3,B3) \
  I4(4, A0,V0,B0, A1,V1,B1, A2,V2,B2, A3,V3,B3) \
  I4(5, A0,V0,B0, A1,V1,B1, A2,V2,B2, A3,V3,B3) \
  I4(6, A0,V0,B0, A1,V1,B1, A2,V2,B2, A3,V3,B3) \
  I4(7, A0,V0,B0, A1,V1,B1, A2,V2,B2, A3,V3,B3) \
  I4(8, A0,V0,B0, A1,V1,B1, A2,V2,B2, A3,V3,B3) \
  I4(9, A0,V0,B0, A1,V1,B1, A2,V2,B2, A3,V3,B3) \
  I4(10, A0,V0,B0, A1,V1,B1, A2,V2,B2, A3,V3,B3) \
  I4(11, A0,V0,B0, A1,V1,B1, A2,V2,B2, A3,V3,B3) \
  I4(12, A0,V0,B0, A1,V1,B1, A2,V2,B2, A3,V3,B3) \
  I4(13, A0,V0,B0, A1,V1,B1, A2,V2,B2, A3,V3,B3) \
  I4(14, A0,V0,B0, A1,V1,B1, A2,V2,B2, A3,V3,B3) \
  I4(15, A0,V0,B0, A1,V1,B1, A2,V2,B2, A3,V3,B3)

// L1 (32 fmacs) split into 4 half-chains: rot 0-7 and rot 8-15 per phase.
#define L1_I4(k) \
  fma_rot<(k)>(a1a, vh1, wreg[(k)]); \
  fma_rot<(k)+8>(a1c, vh1, wreg[8+(k)]); \
  fma_rot<(k)>(a1b, v1s, wreg[16+(k)]); \
  fma_rot<(k)+8>(a1d, v1s, wreg[24+(k)]);

// ---------- guarded producers (VALU-write -> DPP-read needs 2 wait states) ----------
__device__ __forceinline__ float mul_guard(float a, float b) {
  float r;
  asm("v_mul_f32 %0, %1, %2\n\ts_nop 1" : "=v"(r) : "v"(a), "v"(b));
  return r;
}
__device__ __forceinline__ float guard_val(float x) {
  float r;
  asm("v_mov_b32 %0, %1\n\ts_nop 1" : "=v"(r) : "v"(x));
  return r;
}

__device__ __forceinline__ float tanh_u(float x) {  // exp + NR-refined rcp
  x = fminf(10.f, fmaxf(-10.f, x));
  float e = __expf(-2.f * x);
  float d = 1.f + e;
  float r = __builtin_amdgcn_rcpf(d);
  r = r * (2.f - d * r);
  return (1.f - e) * r;
}
__device__ __forceinline__ float tanh_g(float x) {  // guarded final mul (feeds DPP soon)
  x = fminf(10.f, fmaxf(-10.f, x));
  float e = __expf(-2.f * x);
  float d = 1.f + e;
  float r = __builtin_amdgcn_rcpf(d);
  r = r * (2.f - d * r);
  return mul_guard(1.f - e, r);
}

// ---------- prep kernel: weight permutation + vocab table (UNCHANGED) ----------
// Global slot regions (A = [0,192), B = [192,384)):
//  [0,32)    Whh1 (2-phase, packed halves)     A
//  [32,64)   Wih2 (2-phase, v=lane&31)         A
//  [64,128)  Whh2 (4-phase)                    A
//  [128,192) Wih3 (4-phase)                    A
//  [192,256) Whh3 (4-phase)                    B
//  [256,320) Wih3 copy (4-phase)               B
//  [320,384) Wfc  (half-packed, 2-phase x2)    B
// Slot s stored float4-packed: ws[(s>>2)*256 + lane*4 + (s&3)].
__global__ __launch_bounds__(64) void prep_kernel(
    const float* __restrict__ emb,
    const float* __restrict__ Wih1, const float* __restrict__ Whh1,
    const float* __restrict__ bih1, const float* __restrict__ bhh1,
    const float* __restrict__ Wih2, const float* __restrict__ Whh2,
    const float* __restrict__ Wih3, const float* __restrict__ Whh3,
    const float* __restrict__ Wfc,  float* __restrict__ ws) {
  const int lane  = threadIdx.x;
  const int xaddr = ((lane ^ 32) << 2);
  const int s     = blockIdx.x;

  if (s < NSLOT) {
    const float* Wp; int ncol, row, v, p, local, colbase = 0;
    if (s < 32)       { local = s;       v = lane;      Wp = Whh1; ncol = 32; row = lane & 31; p = local >> 4; }
    else if (s < 64)  { local = s - 32;  v = lane & 31; Wp = Wih2; ncol = 32; row = lane;      p = local >> 4; }
    else if (s < 128) { local = s - 64;  v = lane;      Wp = Whh2; ncol = 64; row = lane;      p = local >> 4; }
    else if (s < 192) { local = s - 128; v = lane;      Wp = Wih3; ncol = 64; row = lane;      p = local >> 4; }
    else if (s < 256) { local = s - 192; v = lane;      Wp = Whh3; ncol = 64; row = lane;      p = local >> 4; }
    else if (s < 320) { local = s - 256; v = lane;      Wp = Wih3; ncol = 64; row = lane;      p = local >> 4; }
    else              { local = s - 320; v = lane;      Wp = Wfc;  ncol = 64; row = lane & 31;
                        p = (local >> 4) & 1; colbase = (local >> 5) * 32; }
    int i = local & 15;

    int pv;
    switch (p) {
      case 0: pv = v; break;
      case 1: pv = swz16i(v); break;
      case 2: pv = xor32i(xaddr, v); break;
      default: pv = swz16i(xor32i(xaddr, v)); break;
    }
    int pi = rot_sw(pv, i);

    float w;
    if (s >= 320) {
      int col = (pi & 31) + colbase;
      w = (row < OUTD) ? Wp[row * 64 + col] : 0.f;   // zero-pad rows 26..31
    } else {
      int col = pi & (ncol - 1);
      w = Wp[row * ncol + col];
    }
    ws[(s >> 2) * 256 + lane * 4 + (s & 3)] = w;
  } else {
    // vocab table: tbl[v][j] = emb[v]*W_ih1[j] + b_ih1[j] + b_hh1[j]
    int idx = (s - NSLOT) * 64 + lane;
    if (idx < 27 * 32) {
      int vv = idx >> 5, j = idx & 31;
      float acc = bih1[j] + bhh1[j];
      for (int e = 0; e < 20; ++e) acc += emb[vv * 20 + e] * Wih1[j * 20 + e];
      ws[TBL_OFF + idx] = acc;
    }
  }
}

// ---------- main fused RNN kernel: 2 waves (A,B) per 2 batch elements ----------
__global__ __launch_bounds__(128, 2) void rnn_main(
    const int*   __restrict__ x,
    const float* __restrict__ bih2, const float* __restrict__ bhh2,
    const float* __restrict__ bih3, const float* __restrict__ bhh3,
    const float* __restrict__ bfc,
    const float* __restrict__ ws,   float* __restrict__ out) {
  __shared__ float tbl[27 * 32];
  __shared__ float2 cbuf[2][64];   // double-buffered A->B: {h2_b1, p_sum_b0}

  const int tid   = threadIdx.x;
  const int lane  = tid & 63;
  const bool wA   = (tid < 64);
  const int jlow  = lane & 31;
  // single-hop bpermute addresses
  const int a16   = (lane ^ 16) << 2;              // swz16
  const int a32   = (lane ^ 32) << 2;              // xor32
  const int a48   = (lane ^ 48) << 2;              // swz16 . xor32
  const int alo   = (lane & 31) << 2;              // b0 replicate
  const int ahi   = alo + 128;                     // b1 replicate
  const int alo16 = ((lane & 31) ^ 16) << 2;       // b0 replicate, swz16
  const int ahi16 = alo16 + 128;                   // b1 replicate, swz16

  for (int idx = tid; idx < 27 * 32; idx += 128) tbl[idx] = ws[TBL_OFF + idx];

  // 192 weight slots per wave -> VGPR-resident (constant-indexed only)
  float wreg[192];
  {
    const float4* wsv = (const float4*)ws;
    const int gbase = wA ? 0 : 48;
#pragma unroll
    for (int g = 0; g < 48; ++g) {
      float4 q = wsv[(gbase + g) * 64 + lane];
      wreg[4*g+0] = q.x; wreg[4*g+1] = q.y; wreg[4*g+2] = q.z; wreg[4*g+3] = q.w;
    }
  }
  __syncthreads();

  const int b0   = blockIdx.x * 2;
  const int bsel = b0 + (lane >> 5);        // lanes 0-31 -> b0, 32-63 -> b1

  const float beta2  = bih2[lane] + bhh2[lane];
  const float beta3  = bih3[lane] + bhh3[lane];
  const float betafc = (jlow < OUTD) ? bfc[jlow] : 0.f;

  // Wave-A state
  float vh1 = 0.f, v1s = 0.f;
  float h20 = 0.f, h20a = 0.f, h20b = 0.f, h20c = 0.f;
  float h21 = 0.f, h21a = 0.f, h21b = 0.f, h21c = 0.f;
  // Wave-B state
  float h30 = 0.f, h30a = 0.f, h30b = 0.f, h30c = 0.f;
  float h31 = 0.f, h31a = 0.f, h31b = 0.f, h31c = 0.f;

  int   xv_nxt = 0;
  float tblv_cur = 0.f;
  if (wA) {
    int xv0  = x[bsel];
    tblv_cur = tbl[xv0 * 32 + jlow];
    xv_nxt   = x[BATCH + bsel];
  }
  float* outbase = out + (size_t)bsel * OUTD + jlow;

#pragma unroll 1
  for (int i = 0; i <= SEQ; ++i) {
    __syncthreads();
    if (wA) {
      if (i < SEQ) {
        int tpre   = (i + 2 < SEQ) ? (i + 2) : (SEQ - 1);
        int xv_pre = x[(size_t)tpre * BATCH + bsel];

        // ===== layer 1 (packed halves; K=32; 4 half-chains) =====
        float a1a = tblv_cur, a1b = 0.f, a1c = 0.f, a1d = 0.f;
        L1_I4(0) L1_I4(1) L1_I4(2) L1_I4(3)
        L1_I4(4) L1_I4(5) L1_I4(6) L1_I4(7)
        float h1n = tanh_u((a1a + a1c) + (a1b + a1d));

        // issue all h1 companions (single-hop bpermutes), consumed after L2-recur
        float hb0   = bpermf(alo,   h1n);   // h1_b0[l&31]
        float hb1   = bpermf(ahi,   h1n);   // h1_b1[l&31]
        float hb0s  = bpermf(alo16, h1n);   // h1_b0[(l&31)^16]
        float hb1s  = bpermf(ahi16, h1n);   // h1_b1[(l&31)^16]
        float v1s_n = bpermf(a16,   h1n);
        float tblv_n = tbl[xv_nxt * 32 + jlow];

        // ===== L2 recurrence (independent of h1 -> covers bpermute latency) =====
        float a20 = beta2, a20b = 0.f, a21 = beta2, a21b = 0.f;
        R16_I4(a20, h20,  64, a20b, h20a,  80, a21, h21,  64, a21b, h21a,  80)
        R16_I4(a20, h20b, 96, a20b, h20c, 112, a21, h21b, 96, a21b, h21c, 112)
        // ===== L2 h1-part =====
        R16_I4(a20, hb0,  32, a20b, hb0s,  48, a21, hb1,  32, a21b, hb1s,  48)

        float h2n0 = tanh_g(a20 + a20b);      // feeds DPP (L3 proj) -> guarded
        float h2n0a = bpermf(a16, h2n0);
        float h2n0x = bpermf(a32, h2n0);
        float h2n0c = bpermf(a48, h2n0);
        float h2n1 = tanh_u(a21 + a21b);      // tanh covers h2n0-companion latency
        float h2n1a = bpermf(a16, h2n1);
        float h2n1x = bpermf(a32, h2n1);
        float h2n1c = bpermf(a48, h2n1);

        // ===== L3 input-projection for batch0 (4 independent chains) =====
        float p0 = beta3, p1 = 0.f, p2 = 0.f, p3 = 0.f;
        R16_I4(p0, h2n0, 128, p1, h2n0a, 144, p2, h2n0x, 160, p3, h2n0c, 176)
        float ps = (p0 + p1) + (p2 + p3);

        cbuf[i & 1][lane] = make_float2(h2n1, ps);

        // commit
        vh1 = h1n;  v1s = v1s_n;
        h20 = h2n0; h20a = h2n0a; h20b = h2n0x; h20c = h2n0c;
        h21 = h2n1; h21a = h2n1a; h21b = h2n1x; h21c = h2n1c;
        xv_nxt = xv_pre; tblv_cur = tblv_n;
      }
    } else {
      if (i > 0) {
        float2 c = cbuf[(i - 1) & 1][lane];   // ds_read_b64, consumed late

        // ===== L3 recurrence (independent of LDS read) =====
        float a30 = 0.f, a30b = 0.f, a31 = beta3, a31b = 0.f;
        R16_I4(a30, h30,  0, a30b, h30a, 16, a31, h31,  0, a31b, h31a, 16)
        R16_I4(a30, h30b, 32, a30b, h30c, 48, a31, h31b, 32, a31b, h31c, 48)

        // ===== L3 input-projection for batch1 =====
        float h2n1 = c.x;
        float h2n1a = bpermf(a16, h2n1);
        float h2n1x = bpermf(a32, h2n1);
        float h2n1c = bpermf(a48, h2n1);
        float h3n0 = tanh_u(c.y + (a30 + a30b));   // covers companion latency
        float q0 = 0.f, q1 = 0.f, q2 = 0.f, q3 = 0.f;
        R16_I4(q0, h2n1, 64, q1, h2n1a, 80, q2, h2n1x, 96, q3, h2n1c, 112)
        float h3n1 = tanh_u(((a31 + a31b) + (q0 + q1)) + (q2 + q3));

        float h3n0a = bpermf(a16, h3n0);
        float h3n0x = bpermf(a32, h3n0);
        float h3n0c = bpermf(a48, h3n0);
        float h3n1a = bpermf(a16, h3n1);
        float h3n1x = bpermf(a32, h3n1);
        float h3n1c = bpermf(a48, h3n1);

        // ===== FC (half-packed; vm*s derived from companions, no extra DS) =====
        float vm0  = guard_val((lane < 32) ? h3n0  : h3n1x);  // cols 0..31
        float vm1  = guard_val((lane < 32) ? h3n0x : h3n1 );  // cols 32..63
        float vm0s = guard_val((lane < 32) ? h3n0a : h3n1c);  // swz16(vm0)
        float vm1s = guard_val((lane < 32) ? h3n0c : h3n1a);  // swz16(vm1)
        float af = betafc, afb = 0.f, af2 = 0.f, afb2 = 0.f;
        R16_I4(af, vm0, 128, afb, vm0s, 144, af2, vm1, 160, afb2, vm1s, 176)
        float ov = (af + afb) + (af2 + afb2);
        if (jlow < OUTD) outbase[(size_t)(i - 1) * (BATCH * OUTD)] = ov;

        h30 = h3n0; h30a = h3n0a; h30b = h3n0x; h30c = h3n0c;
        h31 = h3n1; h31a = h3n1a; h31b = h3n1x; h31c = h3n1c;
      }
    }
  }
}

extern "C" void kernel_launch(void* const* d_in, const int* in_sizes, int n_in,
                              void* d_out, int out_size, void* d_ws, size_t ws_size,
                              hipStream_t stream) {
  const int*   x    = (const int*)  d_in[0];
  const float* emb  = (const float*)d_in[1];
  const float* Wih1 = (const float*)d_in[2];
  const float* Whh1 = (const float*)d_in[3];
  const float* bih1 = (const float*)d_in[4];
  const float* bhh1 = (const float*)d_in[5];
  const float* Wih2 = (const float*)d_in[6];
  const float* Whh2 = (const float*)d_in[7];
  const float* bih2 = (const float*)d_in[8];
  const float* bhh2 = (const float*)d_in[9];
  const float* Wih3 = (const float*)d_in[10];
  const float* Whh3 = (const float*)d_in[11];
  const float* bih3 = (const float*)d_in[12];
  const float* bhh3 = (const float*)d_in[13];
  const float* Wfc  = (const float*)d_in[14];
  const float* bfc  = (const float*)d_in[15];
  float* ws  = (float*)d_ws;
  float* out = (float*)d_out;

  prep_kernel<<<NSLOT + 14, 64, 0, stream>>>(emb, Wih1, Whh1, bih1, bhh1,
                                             Wih2, Whh2, Wih3, Whh3, Wfc, ws);
  rnn_main<<<BATCH / 2, 128, 0, stream>>>(x, bih2, bhh2, bih3, bhh3, bfc, ws, out);
}